// Round 13
// baseline (182.593 us; speedup 1.0000x reference)
//
#include <hip/hip_runtime.h>
#include <hip/hip_bf16.h>
#include <hip/hip_fp16.h>

#define N_NODES 100000
#define N_EDGES 1600000
#define D 64
#define NEG_SLOPE 0.2f

#define BSHIFT 9                                   // bucket = dst >> 9
#define BNODES 512                                 // nodes per bucket
#define NBUCK ((N_NODES + BNODES - 1) >> BSHIFT)   // 196
#define BUCKET_CAP 8896    // mean 8192, sigma ~90 -> ~8-sigma headroom
#define P1_EPB 4096        // edges per binning block
#define P1_T 512
#define P1_IT (P1_EPB / P1_T)                      // 8 edges/thread
#define GRID_BIN ((N_EDGES + P1_EPB - 1) / P1_EPB) // 391
#define GEMM_BLKS ((N_NODES + 127) / 128)          // 782

#define HNODES 256                                 // nodes per csr half-block
#define HCAP 4672          // mean 4096, sigma ~64 -> 9-sigma headroom

typedef __attribute__((ext_vector_type(8))) short bf16x8;
typedef __attribute__((ext_vector_type(4))) float f32x4;
#define MFMA16(a, b, c) __builtin_amdgcn_mfma_f32_16x16x32_bf16(a, b, c, 0, 0, 0)

__device__ __forceinline__ short bf16_rne(float f) {
    unsigned u = __float_as_uint(f);
    u += 0x7FFFu + ((u >> 16) & 1u);
    return (short)(u >> 16);
}
__device__ __forceinline__ float bf16_to_f(short h) {
    return __uint_as_float(((unsigned)(unsigned short)h) << 16);
}
// split fp32 -> hi + lo bf16 (two RNE roundings): A@B ~= Ah@Bh + Al@Bh + Ah@Bl
__device__ __forceinline__ void cvt8(float4 f0, float4 f1,
                                     bf16x8& hi, bf16x8& lo) {
    float v[8] = {f0.x, f0.y, f0.z, f0.w, f1.x, f1.y, f1.z, f1.w};
    #pragma unroll
    for (int j = 0; j < 8; ++j) {
        short h = bf16_rne(v[j]);
        hi[j] = h;
        lo[j] = bf16_rne(v[j] - bf16_to_f(h));
    }
}

// shared-memory overlay (union of the two block roles), round-6 proven.
#define SM_BYTES 35152

// ---------------------------------------------------------------------------
// FUSED binning + GEMM kernel -- byte-identical to round 6/12 (proven).
// Blocks [0, GRID_BIN): bin edges by coarse dst bucket, LDS-staged so all
// global writes are coalesced runs. Blocks [GRID_BIN, ..): MFMA GEMM.
// segment_max skipped: softmax is shift-invariant and |e| <= |a0|+|a1| is
// tiny, so exp() cannot overflow -- identical math to the reference.
// ---------------------------------------------------------------------------
__global__ __launch_bounds__(P1_T) void fused_bin_gemm_kernel(
    const float2* __restrict__ rel, const float* __restrict__ attn_e,
    const int* __restrict__ src, const int* __restrict__ dst,
    int* __restrict__ bucket_cursor, uint2* __restrict__ binned,
    const float* __restrict__ feat,
    const float* __restrict__ W_self, const float* __restrict__ W_neigh,
    const float* __restrict__ b_self, const float* __restrict__ b_neigh,
    float* __restrict__ out, __half* __restrict__ g)
{
    __shared__ __align__(16) char smem[SM_BYTES];
    int tid = threadIdx.x;

    if (blockIdx.x >= GRID_BIN) {
        // ---------------- GEMM role ----------------
        bf16x8* wfrag = (bf16x8*)smem;              // 2048 frags, 32 KB
        float* bsum = (float*)(smem + 32768);       // 64 floats
        if (tid < D) bsum[tid] = b_self[tid] + b_neigh[tid];
        for (int c = tid; c < 1024; c += P1_T) {    // W prep, once per block
            int nt = c >> 8;                        // output-feature tile
            int mat = (c >> 7) & 1;                 // 0=self 1=neigh
            int s = (c >> 6) & 1;                   // K-step
            int ln = c & 63;
            const float* Wm = mat ? W_neigh : W_self;
            int row = nt * 16 + (ln & 15);          // A-row = output feature
            int koff = s * 32 + (ln >> 4) * 8;      // k = (lane>>4)*8 + j
            const float4* p = (const float4*)(Wm + row * D + koff);
            bf16x8 hi, lo;
            cvt8(p[0], p[1], hi, lo);
            int base = (c >> 6) * 128 + ln;         // (nt*4+mat*2+s)*128+lane
            wfrag[base] = hi;
            wfrag[base + 64] = lo;
        }
        __syncthreads();

        int lane = tid & 63;
        int wave = tid >> 6;
        int llo = lane & 15;            // B col = node within tile
        int lhi = lane >> 4;            // k-group / C row-group
        int rb = (blockIdx.x - GRID_BIN) * 128 + wave * 16;
        if (rb >= N_NODES) return;      // after the only barrier -> safe

        int node = rb + llo;
        bool valid = node < N_NODES;
        int nclamp = valid ? node : N_NODES - 1;    // tail clamp
        const float4* fr = (const float4*)(feat + (size_t)nclamp * D);
        bf16x8 fhi[2], flo[2];                      // B frags: k=(lhi)*8+j
        #pragma unroll
        for (int s = 0; s < 2; ++s)
            cvt8(fr[s * 8 + lhi * 2], fr[s * 8 + lhi * 2 + 1], fhi[s], flo[s]);

        const float4* bs4 = (const float4*)bsum;
        #pragma unroll
        for (int nt = 0; nt < 4; ++nt) {            // 4 out-feature tiles
            int base = nt * 512 + lane;
            bf16x8 wSh0 = wfrag[base];
            bf16x8 wSl0 = wfrag[base + 64];
            bf16x8 wSh1 = wfrag[base + 128];
            bf16x8 wSl1 = wfrag[base + 192];
            bf16x8 wNh0 = wfrag[base + 256];
            bf16x8 wNl0 = wfrag[base + 320];
            bf16x8 wNh1 = wfrag[base + 384];
            bf16x8 wNl1 = wfrag[base + 448];
            f32x4 accS = {0.f, 0.f, 0.f, 0.f};
            f32x4 accN = {0.f, 0.f, 0.f, 0.f};
            accS = MFMA16(wSh0, fhi[0], accS);
            accN = MFMA16(wNh0, fhi[0], accN);
            accS = MFMA16(wSl0, fhi[0], accS);
            accN = MFMA16(wNl0, fhi[0], accN);
            accS = MFMA16(wSh0, flo[0], accS);
            accN = MFMA16(wNh0, flo[0], accN);
            accS = MFMA16(wSh1, fhi[1], accS);
            accN = MFMA16(wNh1, fhi[1], accN);
            accS = MFMA16(wSl1, fhi[1], accS);
            accN = MFMA16(wNl1, fhi[1], accN);
            accS = MFMA16(wSh1, flo[1], accS);
            accN = MFMA16(wNh1, flo[1], accN);

            if (valid) {
                float4 bb = bs4[nt * 4 + lhi];
                float4 o;
                o.x = accS[0] + bb.x;
                o.y = accS[1] + bb.y;
                o.z = accS[2] + bb.z;
                o.w = accS[3] + bb.w;
                *(float4*)(out + (size_t)node * D + nt * 16 + lhi * 4) = o;
                __half2 hA = __floats2half2_rn(accN[0], accN[1]);
                __half2 hB = __floats2half2_rn(accN[2], accN[3]);
                uint2 gp = make_uint2(*(unsigned*)&hA, *(unsigned*)&hB);
                *(uint2*)(g + (size_t)node * D + nt * 16 + lhi * 4) = gp;
            }
        }
        return;
    }

    // ---------------- binning role ----------------
    uint2* staged2 = (uint2*)smem;                  // bucket-sorted (32 KB)
    int* cnt = (int*)(smem + 32768);
    int* excl = (int*)(smem + 32768 + 784);
    int* chunkbase = (int*)(smem + 32768 + 1568);
    int* wtot = (int*)(smem + 32768 + 2352);

    int e0 = blockIdx.x * P1_EPB;
    int n = min(P1_EPB, N_EDGES - e0);

    for (int b = tid; b < NBUCK; b += P1_T) cnt[b] = 0;
    __syncthreads();

    float a0 = attn_e[0], a1 = attn_e[1];

    uint2 ev[P1_IT];                    // edge payloads, fixed-index -> VGPRs
    int myslot[P1_IT];
    #pragma unroll
    for (int j = 0; j < P1_IT; ++j) {
        int i = tid + j * P1_T;
        if (i < n) {
            int e = e0 + i;
            float2 r = rel[e];
            float sc = r.x * a0 + r.y * a1;
            sc = (sc > 0.f) ? sc : NEG_SLOPE * sc;
            float evx = __expf(sc);
            unsigned u = __float_as_uint(evx) + 0x8000u;    // RNE to bf16
            unsigned wcode = (u >> 16) & 0x7FFFu;           // drop sign (ev>0)
            unsigned s = (unsigned)src[e];
            unsigned d = (unsigned)dst[e];
            ev[j] = make_uint2((s << 15) | wcode, d);
            myslot[j] = atomicAdd(&cnt[d >> BSHIFT], 1);    // local ticket
        }
    }
    __syncthreads();
    // wave-shfl exclusive scan of cnt[0..NBUCK)
    {
        int ln = tid & 63, wv = tid >> 6;
        int c = 0;
        if (tid < 256) c = (tid < NBUCK) ? cnt[tid] : 0;
        int x = c;
        #pragma unroll
        for (int dd = 1; dd < 64; dd <<= 1) {
            int y = __shfl_up(x, dd, 64);
            if (ln >= dd) x += y;
        }
        if (tid < 256 && ln == 63) wtot[wv] = x;
        __syncthreads();
        if (tid < NBUCK) {
            int wbase = 0;
            for (int k = 0; k < wv; ++k) wbase += wtot[k];
            excl[tid] = wbase + x - c;
        }
        __syncthreads();
    }
    #pragma unroll
    for (int j = 0; j < P1_IT; ++j) {   // LDS scatter into bucket order
        int i = tid + j * P1_T;
        if (i < n)
            staged2[excl[ev[j].y >> BSHIFT] + myslot[j]] = ev[j];
    }
    if (tid < NBUCK)                    // reserve contiguous global chunks
        chunkbase[tid] = atomicAdd(&bucket_cursor[tid], cnt[tid]);
    __syncthreads();
    for (int i = tid; i < n; i += P1_T) {  // coalesced runs per bucket chunk
        uint2 v = staged2[i];
        int b = (int)(v.y >> BSHIFT);
        binned[(size_t)b * BUCKET_CAP + chunkbase[b] + (i - excl[b])] = v;
    }
}

// ---------------------------------------------------------------------------
// Pass 2: TWO blocks per bucket (filter on dst bit 8) -- round-8 passed
// body, now applied as the ONLY change vs round 12 for clean attribution
// (r8 bundled it with an aggregate regression). Rationale: full-bucket csr
// = 196 blocks x 1024 thr x 35.6 KB -> 1 block/CU, 60 CUs idle, ~8400
// edges serialized through 512 LDS-atomic bins. 392 half-blocks (~22 KB
// LDS) are all co-resident and halve per-block histogram/scatter work;
// each half re-reads the full bucket (L2-hot, cheap). Half-1's base =
// bucket_base + (count - own_total): no cross-block communication.
// ---------------------------------------------------------------------------
__global__ __launch_bounds__(1024) void csr_kernel(
    const int* __restrict__ bucket_cursor, const uint2* __restrict__ binned,
    int* __restrict__ offsets, unsigned* __restrict__ edata)
{
    __shared__ unsigned vals[HCAP];         // 18.7 KB
    __shared__ int hist[HNODES];
    __shared__ int nexcl[HNODES];
    __shared__ int cur[HNODES];
    __shared__ int wtot[4];
    __shared__ int bc[NBUCK];
    __shared__ int base_sh, htot_sh;

    int tid = threadIdx.x;
    int b = blockIdx.x >> 1;
    unsigned half = blockIdx.x & 1;

    if (tid < NBUCK) bc[tid] = bucket_cursor[tid];
    if (tid < HNODES) { hist[tid] = 0; cur[tid] = 0; }
    __syncthreads();
    if (tid == 0) {
        int s = 0;
        for (int i = 0; i < b; ++i) s += bc[i];
        base_sh = s;
    }
    __syncthreads();
    int count = bc[b];
    const uint2* bin = binned + (size_t)b * BUCKET_CAP;

    for (int i = tid; i < count; i += 1024) {       // filtered histogram
        unsigned d = bin[i].y;
        if (((d >> 8) & 1u) == half)
            atomicAdd(&hist[d & (HNODES - 1)], 1);
    }
    __syncthreads();

    // wave-shfl scan over 256 bins (waves 0-3)
    {
        int ln = tid & 63, wv = tid >> 6;
        int h = 0, x = 0;
        if (tid < HNODES) {
            h = hist[tid];
            x = h;
            #pragma unroll
            for (int dd = 1; dd < 64; dd <<= 1) {
                int y = __shfl_up(x, dd, 64);
                if (ln >= dd) x += y;
            }
            if (ln == 63) wtot[wv] = x;
        }
        __syncthreads();
        if (tid < HNODES) {
            int wbase = 0;
            for (int k = 0; k < wv; ++k) wbase += wtot[k];
            nexcl[tid] = wbase + x - h;              // exclusive prefix
            if (tid == HNODES - 1) htot_sh = wbase + x;   // this half's total
        }
        __syncthreads();
    }
    int hcount = htot_sh;
    int base = base_sh + (half ? (count - hcount) : 0);

    int node = (b << BSHIFT) + (int)half * HNODES + tid;
    if (tid < HNODES && node < N_NODES) offsets[node] = base + nexcl[tid];
    if (b == NBUCK - 1 && half == 1 && tid == 0) offsets[N_NODES] = N_EDGES;

    for (int i = tid; i < count; i += 1024) {       // filtered LDS scatter
        uint2 e = bin[i];
        if (((e.y >> 8) & 1u) == half) {
            int d = e.y & (HNODES - 1);
            int t = atomicAdd(&cur[d], 1);
            vals[nexcl[d] + t] = e.x;
        }
    }
    __syncthreads();
    for (int i = tid; i < hcount; i += 1024)        // coalesced flush
        edata[base + i] = vals[i];
}

// ---------------------------------------------------------------------------
// Aggregation: byte-identical to round 12 (best measured: 42.0us, VALU 58%
// || HBM 36% largely overlapped -- at its practical floor across 6 variants).
// 4-deep MLP + fp16 v_fma_mix decode; lane = 16*q + t; 16 edges/iter.
// ---------------------------------------------------------------------------
__global__ __launch_bounds__(256) void aggregate_kernel(
    const __half* __restrict__ g, const unsigned* __restrict__ edata,
    const int* __restrict__ offsets, float* __restrict__ out)
{
    int v = blockIdx.x * 4 + (threadIdx.x >> 6);   // 25000*4 == N exactly
    int lane = threadIdx.x & 63;
    int q = lane >> 4;                 // edge group (0..3)
    int t = lane & 15;                 // feature quad: features 4t..4t+3
    int lo = offsets[v], hi = offsets[v + 1];
    float4 acc = make_float4(0.f, 0.f, 0.f, 0.f);
    float sum = 0.f;

    for (int i = lo; i < hi; i += 16) {
        int e0 = i + q;
        int e1 = i + 4 + q;
        int e2 = i + 8 + q;
        int e3 = i + 12 + q;
        int ec0 = (e0 < hi) ? e0 : hi - 1;         // in-bounds (loop => hi>lo)
        int ec1 = (e1 < hi) ? e1 : hi - 1;
        int ec2 = (e2 < hi) ? e2 : hi - 1;
        int ec3 = (e3 < hi) ? e3 : hi - 1;
        unsigned p0 = edata[ec0];                  // coalesced, L2-hot
        unsigned p1 = edata[ec1];
        unsigned p2 = edata[ec2];
        unsigned p3 = edata[ec3];
        float w0 = (e0 < hi) ? __uint_as_float((p0 & 0x7FFFu) << 16) : 0.f;
        float w1 = (e1 < hi) ? __uint_as_float((p1 & 0x7FFFu) << 16) : 0.f;
        float w2 = (e2 < hi) ? __uint_as_float((p2 & 0x7FFFu) << 16) : 0.f;
        float w3 = (e3 < hi) ? __uint_as_float((p3 & 0x7FFFu) << 16) : 0.f;
        const uint2* r0 = (const uint2*)(g + (size_t)(p0 >> 15) * D);
        const uint2* r1 = (const uint2*)(g + (size_t)(p1 >> 15) * D);
        const uint2* r2 = (const uint2*)(g + (size_t)(p2 >> 15) * D);
        const uint2* r3 = (const uint2*)(g + (size_t)(p3 >> 15) * D);
        uint2 u0 = r0[t];                          // 4 gathers in flight
        uint2 u1 = r1[t];
        uint2 u2 = r2[t];
        uint2 u3 = r3[t];
        float2 f;
        f = __half22float2(*(const __half2*)&u0.x);
        acc.x = fmaf(w0, f.x, acc.x); acc.y = fmaf(w0, f.y, acc.y);
        f = __half22float2(*(const __half2*)&u0.y);
        acc.z = fmaf(w0, f.x, acc.z); acc.w = fmaf(w0, f.y, acc.w);
        sum += w0;
        f = __half22float2(*(const __half2*)&u1.x);
        acc.x = fmaf(w1, f.x, acc.x); acc.y = fmaf(w1, f.y, acc.y);
        f = __half22float2(*(const __half2*)&u1.y);
        acc.z = fmaf(w1, f.x, acc.z); acc.w = fmaf(w1, f.y, acc.w);
        sum += w1;
        f = __half22float2(*(const __half2*)&u2.x);
        acc.x = fmaf(w2, f.x, acc.x); acc.y = fmaf(w2, f.y, acc.y);
        f = __half22float2(*(const __half2*)&u2.y);
        acc.z = fmaf(w2, f.x, acc.z); acc.w = fmaf(w2, f.y, acc.w);
        sum += w2;
        f = __half22float2(*(const __half2*)&u3.x);
        acc.x = fmaf(w3, f.x, acc.x); acc.y = fmaf(w3, f.y, acc.y);
        f = __half22float2(*(const __half2*)&u3.y);
        acc.z = fmaf(w3, f.x, acc.z); acc.w = fmaf(w3, f.y, acc.w);
        sum += w3;
    }
    // combine the 4 groups (each lane t holds partials for feats 4t..4t+3)
    #pragma unroll
    for (int mm = 16; mm <= 32; mm <<= 1) {
        acc.x += __shfl_xor(acc.x, mm, 64);
        acc.y += __shfl_xor(acc.y, mm, 64);
        acc.z += __shfl_xor(acc.z, mm, 64);
        acc.w += __shfl_xor(acc.w, mm, 64);
        sum   += __shfl_xor(sum,   mm, 64);
    }
    if (hi > lo && q == 0) {                       // 16 lanes: float4 each
        float inv = 1.f / sum;
        float4* orow = (float4*)(out + (size_t)v * D);
        float4 c = orow[t];
        c.x += acc.x * inv; c.y += acc.y * inv;
        c.z += acc.z * inv; c.w += acc.w * inv;
        orow[t] = c;
    }
    // zero-degree nodes: reference gives h_neigh = 0 -> out keeps self part
}

// ---------------------------------------------------------------------------
extern "C" void kernel_launch(void* const* d_in, const int* in_sizes, int n_in,
                              void* d_out, int out_size, void* d_ws, size_t ws_size,
                              hipStream_t stream) {
    const float* feat    = (const float*)d_in[0];
    const float* rel     = (const float*)d_in[1];
    const float* W_self  = (const float*)d_in[2];
    const float* b_self  = (const float*)d_in[3];
    const float* W_neigh = (const float*)d_in[4];
    const float* b_neigh = (const float*)d_in[5];
    const float* attn_e  = (const float*)d_in[6];
    const int*   src     = (const int*)d_in[7];
    const int*   dst     = (const int*)d_in[8];
    float* out = (float*)d_out;

    // workspace layout (~33.6 MB), all segments 16B-aligned
    uint2* binned = (uint2*)d_ws;                               // 13.95 MB
    __half* g = (__half*)(binned + (size_t)NBUCK * BUCKET_CAP); // 12.8 MB
    unsigned* edata = (unsigned*)((char*)g + (size_t)N_NODES * D * 2); // 6.4 MB
    int* offsets = (int*)(edata + N_EDGES);                     // [N+1]
    int* bucket_cursor = offsets + N_NODES + 1;                 // [NBUCK]

    hipMemsetAsync(bucket_cursor, 0, NBUCK * sizeof(int), stream);

    fused_bin_gemm_kernel<<<GRID_BIN + GEMM_BLKS, P1_T, 0, stream>>>(
        (const float2*)rel, attn_e, src, dst, bucket_cursor, binned,
        feat, W_self, W_neigh, b_self, b_neigh, out, g);
    csr_kernel<<<NBUCK * 2, 1024, 0, stream>>>(
        bucket_cursor, binned, offsets, edata);
    aggregate_kernel<<<N_NODES / 4, 256, 0, stream>>>(
        g, edata, offsets, out);
}

// Round 14
// 177.029 us; speedup vs baseline: 1.0314x; 1.0314x over previous
//
#include <hip/hip_runtime.h>
#include <hip/hip_bf16.h>
#include <hip/hip_fp16.h>

#define N_NODES 100000
#define N_EDGES 1600000
#define D 64
#define NEG_SLOPE 0.2f

#define BSHIFT 9                                   // bucket = dst >> 9
#define BNODES 512                                 // nodes per bucket
#define NBUCK ((N_NODES + BNODES - 1) >> BSHIFT)   // 196
#define BUCKET_CAP 8896    // mean 8192, sigma ~90 -> ~8-sigma headroom
#define P1_EPB 4096        // edges per binning block
#define P1_T 512
#define P1_IT (P1_EPB / P1_T)                      // 8 edges/thread
#define GRID_BIN ((N_EDGES + P1_EPB - 1) / P1_EPB) // 391
#define GEMM_BLKS ((N_NODES + 127) / 128)          // 782

typedef __attribute__((ext_vector_type(8))) short bf16x8;
typedef __attribute__((ext_vector_type(4))) float f32x4;
#define MFMA16(a, b, c) __builtin_amdgcn_mfma_f32_16x16x32_bf16(a, b, c, 0, 0, 0)

__device__ __forceinline__ short bf16_rne(float f) {
    unsigned u = __float_as_uint(f);
    u += 0x7FFFu + ((u >> 16) & 1u);
    return (short)(u >> 16);
}
__device__ __forceinline__ float bf16_to_f(short h) {
    return __uint_as_float(((unsigned)(unsigned short)h) << 16);
}
// split fp32 -> hi + lo bf16 (two RNE roundings): A@B ~= Ah@Bh + Al@Bh + Ah@Bl
__device__ __forceinline__ void cvt8(float4 f0, float4 f1,
                                     bf16x8& hi, bf16x8& lo) {
    float v[8] = {f0.x, f0.y, f0.z, f0.w, f1.x, f1.y, f1.z, f1.w};
    #pragma unroll
    for (int j = 0; j < 8; ++j) {
        short h = bf16_rne(v[j]);
        hi[j] = h;
        lo[j] = bf16_rne(v[j] - bf16_to_f(h));
    }
}

// shared-memory overlay (union of the two block roles), round-6 proven.
#define SM_BYTES 35152

// ---------------------------------------------------------------------------
// FUSED binning + GEMM kernel -- byte-identical to round 6/12 (proven best).
// Blocks [0, GRID_BIN): bin edges by coarse dst bucket, LDS-staged so all
// global writes are coalesced runs. Blocks [GRID_BIN, ..): MFMA GEMM.
// Round-13 post-mortem: half-bucket csr was the ONLY change and regressed
// 178.2 -> 182.6; full-bucket csr (below) is proven best. This round locks
// in the best-measured configuration (r12): every lever has been isolated
// at least once -- fusion/regroup (r4/r7/r9/r10/r11), persistent waves
// (r5), occupancy (r6), csr split (r8/r13), aggregate MLP/decode (r2/r12).
// segment_max skipped: softmax is shift-invariant and |e| <= |a0|+|a1| is
// tiny, so exp() cannot overflow -- identical math to the reference.
// ---------------------------------------------------------------------------
__global__ __launch_bounds__(P1_T) void fused_bin_gemm_kernel(
    const float2* __restrict__ rel, const float* __restrict__ attn_e,
    const int* __restrict__ src, const int* __restrict__ dst,
    int* __restrict__ bucket_cursor, uint2* __restrict__ binned,
    const float* __restrict__ feat,
    const float* __restrict__ W_self, const float* __restrict__ W_neigh,
    const float* __restrict__ b_self, const float* __restrict__ b_neigh,
    float* __restrict__ out, __half* __restrict__ g)
{
    __shared__ __align__(16) char smem[SM_BYTES];
    int tid = threadIdx.x;

    if (blockIdx.x >= GRID_BIN) {
        // ---------------- GEMM role ----------------
        bf16x8* wfrag = (bf16x8*)smem;              // 2048 frags, 32 KB
        float* bsum = (float*)(smem + 32768);       // 64 floats
        if (tid < D) bsum[tid] = b_self[tid] + b_neigh[tid];
        for (int c = tid; c < 1024; c += P1_T) {    // W prep, once per block
            int nt = c >> 8;                        // output-feature tile
            int mat = (c >> 7) & 1;                 // 0=self 1=neigh
            int s = (c >> 6) & 1;                   // K-step
            int ln = c & 63;
            const float* Wm = mat ? W_neigh : W_self;
            int row = nt * 16 + (ln & 15);          // A-row = output feature
            int koff = s * 32 + (ln >> 4) * 8;      // k = (lane>>4)*8 + j
            const float4* p = (const float4*)(Wm + row * D + koff);
            bf16x8 hi, lo;
            cvt8(p[0], p[1], hi, lo);
            int base = (c >> 6) * 128 + ln;         // (nt*4+mat*2+s)*128+lane
            wfrag[base] = hi;
            wfrag[base + 64] = lo;
        }
        __syncthreads();

        int lane = tid & 63;
        int wave = tid >> 6;
        int llo = lane & 15;            // B col = node within tile
        int lhi = lane >> 4;            // k-group / C row-group
        int rb = (blockIdx.x - GRID_BIN) * 128 + wave * 16;
        if (rb >= N_NODES) return;      // after the only barrier -> safe

        int node = rb + llo;
        bool valid = node < N_NODES;
        int nclamp = valid ? node : N_NODES - 1;    // tail clamp
        const float4* fr = (const float4*)(feat + (size_t)nclamp * D);
        bf16x8 fhi[2], flo[2];                      // B frags: k=(lhi)*8+j
        #pragma unroll
        for (int s = 0; s < 2; ++s)
            cvt8(fr[s * 8 + lhi * 2], fr[s * 8 + lhi * 2 + 1], fhi[s], flo[s]);

        const float4* bs4 = (const float4*)bsum;
        #pragma unroll
        for (int nt = 0; nt < 4; ++nt) {            // 4 out-feature tiles
            int base = nt * 512 + lane;
            bf16x8 wSh0 = wfrag[base];
            bf16x8 wSl0 = wfrag[base + 64];
            bf16x8 wSh1 = wfrag[base + 128];
            bf16x8 wSl1 = wfrag[base + 192];
            bf16x8 wNh0 = wfrag[base + 256];
            bf16x8 wNl0 = wfrag[base + 320];
            bf16x8 wNh1 = wfrag[base + 384];
            bf16x8 wNl1 = wfrag[base + 448];
            f32x4 accS = {0.f, 0.f, 0.f, 0.f};
            f32x4 accN = {0.f, 0.f, 0.f, 0.f};
            accS = MFMA16(wSh0, fhi[0], accS);
            accN = MFMA16(wNh0, fhi[0], accN);
            accS = MFMA16(wSl0, fhi[0], accS);
            accN = MFMA16(wNl0, fhi[0], accN);
            accS = MFMA16(wSh0, flo[0], accS);
            accN = MFMA16(wNh0, flo[0], accN);
            accS = MFMA16(wSh1, fhi[1], accS);
            accN = MFMA16(wNh1, fhi[1], accN);
            accS = MFMA16(wSl1, fhi[1], accS);
            accN = MFMA16(wNl1, fhi[1], accN);
            accS = MFMA16(wSh1, flo[1], accS);
            accN = MFMA16(wNh1, flo[1], accN);

            if (valid) {
                float4 bb = bs4[nt * 4 + lhi];
                float4 o;
                o.x = accS[0] + bb.x;
                o.y = accS[1] + bb.y;
                o.z = accS[2] + bb.z;
                o.w = accS[3] + bb.w;
                *(float4*)(out + (size_t)node * D + nt * 16 + lhi * 4) = o;
                __half2 hA = __floats2half2_rn(accN[0], accN[1]);
                __half2 hB = __floats2half2_rn(accN[2], accN[3]);
                uint2 gp = make_uint2(*(unsigned*)&hA, *(unsigned*)&hB);
                *(uint2*)(g + (size_t)node * D + nt * 16 + lhi * 4) = gp;
            }
        }
        return;
    }

    // ---------------- binning role ----------------
    uint2* staged2 = (uint2*)smem;                  // bucket-sorted (32 KB)
    int* cnt = (int*)(smem + 32768);
    int* excl = (int*)(smem + 32768 + 784);
    int* chunkbase = (int*)(smem + 32768 + 1568);
    int* wtot = (int*)(smem + 32768 + 2352);

    int e0 = blockIdx.x * P1_EPB;
    int n = min(P1_EPB, N_EDGES - e0);

    for (int b = tid; b < NBUCK; b += P1_T) cnt[b] = 0;
    __syncthreads();

    float a0 = attn_e[0], a1 = attn_e[1];

    uint2 ev[P1_IT];                    // edge payloads, fixed-index -> VGPRs
    int myslot[P1_IT];
    #pragma unroll
    for (int j = 0; j < P1_IT; ++j) {
        int i = tid + j * P1_T;
        if (i < n) {
            int e = e0 + i;
            float2 r = rel[e];
            float sc = r.x * a0 + r.y * a1;
            sc = (sc > 0.f) ? sc : NEG_SLOPE * sc;
            float evx = __expf(sc);
            unsigned u = __float_as_uint(evx) + 0x8000u;    // RNE to bf16
            unsigned wcode = (u >> 16) & 0x7FFFu;           // drop sign (ev>0)
            unsigned s = (unsigned)src[e];
            unsigned d = (unsigned)dst[e];
            ev[j] = make_uint2((s << 15) | wcode, d);
            myslot[j] = atomicAdd(&cnt[d >> BSHIFT], 1);    // local ticket
        }
    }
    __syncthreads();
    // wave-shfl exclusive scan of cnt[0..NBUCK)
    {
        int ln = tid & 63, wv = tid >> 6;
        int c = 0;
        if (tid < 256) c = (tid < NBUCK) ? cnt[tid] : 0;
        int x = c;
        #pragma unroll
        for (int dd = 1; dd < 64; dd <<= 1) {
            int y = __shfl_up(x, dd, 64);
            if (ln >= dd) x += y;
        }
        if (tid < 256 && ln == 63) wtot[wv] = x;
        __syncthreads();
        if (tid < NBUCK) {
            int wbase = 0;
            for (int k = 0; k < wv; ++k) wbase += wtot[k];
            excl[tid] = wbase + x - c;
        }
        __syncthreads();
    }
    #pragma unroll
    for (int j = 0; j < P1_IT; ++j) {   // LDS scatter into bucket order
        int i = tid + j * P1_T;
        if (i < n)
            staged2[excl[ev[j].y >> BSHIFT] + myslot[j]] = ev[j];
    }
    if (tid < NBUCK)                    // reserve contiguous global chunks
        chunkbase[tid] = atomicAdd(&bucket_cursor[tid], cnt[tid]);
    __syncthreads();
    for (int i = tid; i < n; i += P1_T) {  // coalesced runs per bucket chunk
        uint2 v = staged2[i];
        int b = (int)(v.y >> BSHIFT);
        binned[(size_t)b * BUCKET_CAP + chunkbase[b] + (i - excl[b])] = v;
    }
}

// ---------------------------------------------------------------------------
// Pass 2 (byte-identical to round-6/12 proven): one FULL bucket per block,
// 1024 threads. LDS histogram -> wave-shfl scan -> write offsets -> LDS
// scatter of packed values -> coalesced flush. (Half-bucket split measured
// SLOWER in r8 and r13: double bucket re-read > parallelism gain.)
// ---------------------------------------------------------------------------
__global__ __launch_bounds__(1024) void csr_kernel(
    const int* __restrict__ bucket_cursor, const uint2* __restrict__ binned,
    int* __restrict__ offsets, unsigned* __restrict__ edata)
{
    __shared__ unsigned vals[BUCKET_CAP];   // 35.6 KB
    __shared__ int hist[BNODES];
    __shared__ int nexcl[BNODES];
    __shared__ int cur[BNODES];
    __shared__ int bc[NBUCK];
    __shared__ int wtot[8];
    __shared__ int base_sh;

    int b = blockIdx.x;
    int tid = threadIdx.x;

    if (tid < NBUCK) bc[tid] = bucket_cursor[tid];
    if (tid < BNODES) { hist[tid] = 0; cur[tid] = 0; }
    __syncthreads();
    if (tid == 0) {
        int s = 0;
        for (int i = 0; i < b; ++i) s += bc[i];
        base_sh = s;
    }
    __syncthreads();
    int count = bc[b];
    int base = base_sh;
    const uint2* bin = binned + (size_t)b * BUCKET_CAP;

    for (int i = tid; i < count; i += 1024)
        atomicAdd(&hist[bin[i].y & (BNODES - 1)], 1);
    __syncthreads();

    // wave-shfl scan: waves 0..7 hold one bin per lane
    {
        int ln = tid & 63, wv = tid >> 6;
        int h = 0;
        if (tid < BNODES) h = hist[tid];
        int x = h;
        #pragma unroll
        for (int dd = 1; dd < 64; dd <<= 1) {
            int y = __shfl_up(x, dd, 64);
            if (ln >= dd) x += y;
        }
        if (tid < BNODES && ln == 63) wtot[wv] = x;
        __syncthreads();
        if (tid < BNODES) {
            int wbase = 0;
            for (int k = 0; k < wv; ++k) wbase += wtot[k];
            nexcl[tid] = wbase + x - h;              // exclusive prefix
        }
        __syncthreads();
    }

    int node = (b << BSHIFT) + tid;
    if (tid < BNODES && node < N_NODES) offsets[node] = base + nexcl[tid];
    if (b == NBUCK - 1 && tid == 0) offsets[N_NODES] = N_EDGES;

    for (int i = tid; i < count; i += 1024) {     // LDS scatter
        uint2 e = bin[i];
        int d = e.y & (BNODES - 1);
        int t = atomicAdd(&cur[d], 1);
        vals[nexcl[d] + t] = e.x;
    }
    __syncthreads();
    for (int i = tid; i < count; i += 1024)       // coalesced flush
        edata[base + i] = vals[i];
}

// ---------------------------------------------------------------------------
// Aggregation: byte-identical to round 12 (best measured: 42.0us). 4-deep
// MLP + fp16 v_fma_mix decode; lane = 16*q + t, q = edge group, t = feature
// quad (uint2 = 4 fp16); 16 edges/iter = mean degree, 4 gathers in flight.
// At its fabric floor: 94 MB FETCH / 2.9 TB/s ~= 32us + reduce tail;
// VALU 56% || HBM 36% largely overlapped across 6 measured variants.
// ---------------------------------------------------------------------------
__global__ __launch_bounds__(256) void aggregate_kernel(
    const __half* __restrict__ g, const unsigned* __restrict__ edata,
    const int* __restrict__ offsets, float* __restrict__ out)
{
    int v = blockIdx.x * 4 + (threadIdx.x >> 6);   // 25000*4 == N exactly
    int lane = threadIdx.x & 63;
    int q = lane >> 4;                 // edge group (0..3)
    int t = lane & 15;                 // feature quad: features 4t..4t+3
    int lo = offsets[v], hi = offsets[v + 1];
    float4 acc = make_float4(0.f, 0.f, 0.f, 0.f);
    float sum = 0.f;

    for (int i = lo; i < hi; i += 16) {
        int e0 = i + q;
        int e1 = i + 4 + q;
        int e2 = i + 8 + q;
        int e3 = i + 12 + q;
        int ec0 = (e0 < hi) ? e0 : hi - 1;         // in-bounds (loop => hi>lo)
        int ec1 = (e1 < hi) ? e1 : hi - 1;
        int ec2 = (e2 < hi) ? e2 : hi - 1;
        int ec3 = (e3 < hi) ? e3 : hi - 1;
        unsigned p0 = edata[ec0];                  // coalesced, L2-hot
        unsigned p1 = edata[ec1];
        unsigned p2 = edata[ec2];
        unsigned p3 = edata[ec3];
        float w0 = (e0 < hi) ? __uint_as_float((p0 & 0x7FFFu) << 16) : 0.f;
        float w1 = (e1 < hi) ? __uint_as_float((p1 & 0x7FFFu) << 16) : 0.f;
        float w2 = (e2 < hi) ? __uint_as_float((p2 & 0x7FFFu) << 16) : 0.f;
        float w3 = (e3 < hi) ? __uint_as_float((p3 & 0x7FFFu) << 16) : 0.f;
        const uint2* r0 = (const uint2*)(g + (size_t)(p0 >> 15) * D);
        const uint2* r1 = (const uint2*)(g + (size_t)(p1 >> 15) * D);
        const uint2* r2 = (const uint2*)(g + (size_t)(p2 >> 15) * D);
        const uint2* r3 = (const uint2*)(g + (size_t)(p3 >> 15) * D);
        uint2 u0 = r0[t];                          // 4 gathers in flight
        uint2 u1 = r1[t];
        uint2 u2 = r2[t];
        uint2 u3 = r3[t];
        float2 f;
        f = __half22float2(*(const __half2*)&u0.x);
        acc.x = fmaf(w0, f.x, acc.x); acc.y = fmaf(w0, f.y, acc.y);
        f = __half22float2(*(const __half2*)&u0.y);
        acc.z = fmaf(w0, f.x, acc.z); acc.w = fmaf(w0, f.y, acc.w);
        sum += w0;
        f = __half22float2(*(const __half2*)&u1.x);
        acc.x = fmaf(w1, f.x, acc.x); acc.y = fmaf(w1, f.y, acc.y);
        f = __half22float2(*(const __half2*)&u1.y);
        acc.z = fmaf(w1, f.x, acc.z); acc.w = fmaf(w1, f.y, acc.w);
        sum += w1;
        f = __half22float2(*(const __half2*)&u2.x);
        acc.x = fmaf(w2, f.x, acc.x); acc.y = fmaf(w2, f.y, acc.y);
        f = __half22float2(*(const __half2*)&u2.y);
        acc.z = fmaf(w2, f.x, acc.z); acc.w = fmaf(w2, f.y, acc.w);
        sum += w2;
        f = __half22float2(*(const __half2*)&u3.x);
        acc.x = fmaf(w3, f.x, acc.x); acc.y = fmaf(w3, f.y, acc.y);
        f = __half22float2(*(const __half2*)&u3.y);
        acc.z = fmaf(w3, f.x, acc.z); acc.w = fmaf(w3, f.y, acc.w);
        sum += w3;
    }
    // combine the 4 groups (each lane t holds partials for feats 4t..4t+3)
    #pragma unroll
    for (int mm = 16; mm <= 32; mm <<= 1) {
        acc.x += __shfl_xor(acc.x, mm, 64);
        acc.y += __shfl_xor(acc.y, mm, 64);
        acc.z += __shfl_xor(acc.z, mm, 64);
        acc.w += __shfl_xor(acc.w, mm, 64);
        sum   += __shfl_xor(sum,   mm, 64);
    }
    if (hi > lo && q == 0) {                       // 16 lanes: float4 each
        float inv = 1.f / sum;
        float4* orow = (float4*)(out + (size_t)v * D);
        float4 c = orow[t];
        c.x += acc.x * inv; c.y += acc.y * inv;
        c.z += acc.z * inv; c.w += acc.w * inv;
        orow[t] = c;
    }
    // zero-degree nodes: reference gives h_neigh = 0 -> out keeps self part
}

// ---------------------------------------------------------------------------
extern "C" void kernel_launch(void* const* d_in, const int* in_sizes, int n_in,
                              void* d_out, int out_size, void* d_ws, size_t ws_size,
                              hipStream_t stream) {
    const float* feat    = (const float*)d_in[0];
    const float* rel     = (const float*)d_in[1];
    const float* W_self  = (const float*)d_in[2];
    const float* b_self  = (const float*)d_in[3];
    const float* W_neigh = (const float*)d_in[4];
    const float* b_neigh = (const float*)d_in[5];
    const float* attn_e  = (const float*)d_in[6];
    const int*   src     = (const int*)d_in[7];
    const int*   dst     = (const int*)d_in[8];
    float* out = (float*)d_out;

    // workspace layout (~33.6 MB), all segments 16B-aligned
    uint2* binned = (uint2*)d_ws;                               // 13.95 MB
    __half* g = (__half*)(binned + (size_t)NBUCK * BUCKET_CAP); // 12.8 MB
    unsigned* edata = (unsigned*)((char*)g + (size_t)N_NODES * D * 2); // 6.4 MB
    int* offsets = (int*)(edata + N_EDGES);                     // [N+1]
    int* bucket_cursor = offsets + N_NODES + 1;                 // [NBUCK]

    hipMemsetAsync(bucket_cursor, 0, NBUCK * sizeof(int), stream);

    fused_bin_gemm_kernel<<<GRID_BIN + GEMM_BLKS, P1_T, 0, stream>>>(
        (const float2*)rel, attn_e, src, dst, bucket_cursor, binned,
        feat, W_self, W_neigh, b_self, b_neigh, out, g);
    csr_kernel<<<NBUCK, 1024, 0, stream>>>(
        bucket_cursor, binned, offsets, edata);
    aggregate_kernel<<<N_NODES / 4, 256, 0, stream>>>(
        g, edata, offsets, out);
}